// Round 11
// baseline (88.216 us; speedup 1.0000x reference)
//
#include <hip/hip_runtime.h>
#include <cstddef>

#define EPS 1e-6f
constexpr float INV_SQRT_E = 0.6065306597126334f;  // exp(-0.5*THETA^2), THETA=1

// R9 structure (32 waves/CU, best measured) with ONE change: the SAD pass
// reads taps from GLOBAL memory (x is 2 MB -> L1/L2 resident; wave-coalesced
// 256 B per tap-read) instead of LDS. Rationale: kernel is LDS-unit
// instruction-throughput bound (~11K LDS instrs/CU x ~5.5 cyc ~= measured
// 24 us dispatch); SAD was 164 b32 reads/px ~= half the LDS port time. VMEM
// is a different port and overlaps across waves. Border blocks take a
// clamped+masked path (block-uniform branch); interior blocks unguarded.
template <int D>
__device__ __forceinline__ void body(const float* __restrict__ x,
                                     float* __restrict__ out,
                                     char* smem, int bc, int H, int W)
{
    constexpr int PAD = D * D;          // halo per side
    constexpr int KS  = 2 * D + 1;      // taps per axis
    constexpr int K   = KS * KS;        // patch size
    constexpr int TW  = 64, TH = 8;
    constexpr int LW  = TW + 2 * PAD;
    constexpr int LH  = TH + 2 * PAD;
    constexpr int NE  = LH * LW;
    constexpr int NI  = (NE + 511) / 512;
    constexpr float INVK = 1.0f / (float)K;
    constexpr float UNB  = (float)K / (float)(K - 1);

    float2* sv  = (float2*)smem;                          // {v, v*log(v+eps)}
    float2* cs2 = (float2*)(smem + LH * LW * 8);          // {col_s, col_s2}
    float*  cs1 = (float*) (smem + LH * LW * 8 + TH * LW * 8);  // col_sl

    const int w0 = blockIdx.x * TW;
    const int h0 = blockIdx.y * TH;
    const float* xp = x + (size_t)bc * H * W;
    const int tid = threadIdx.y * 64 + threadIdx.x;

    // ---- Staging: batched loads, then LDS writes. ----
    float vb[NI];
    #pragma unroll
    for (int i = 0; i < NI; ++i) {
        const int idx = tid + i * 512;
        float v = 0.0f;
        if (idx < NE) {
            const int r  = idx / LW;
            const int cc = idx - r * LW;
            const int gh = h0 - PAD + r;
            const int gw = w0 - PAD + cc;
            if (gh >= 0 && gh < H && gw >= 0 && gw < W) v = xp[gh * W + gw];
        }
        vb[i] = v;
    }
    #pragma unroll
    for (int i = 0; i < NI; ++i) {
        const int idx = tid + i * 512;
        if (idx < NE)
            sv[idx] = make_float2(vb[i], vb[i] * __logf(vb[i] + EPS));
    }
    __syncthreads();

    const int tx = threadIdx.x;
    const int ty = threadIdx.y;

    float s = 0.0f, s2 = 0.0f, sl = 0.0f;
    float sad;

    if constexpr (K <= 9) {
        // D=1: single pass, taps cached in registers (LDS-light already).
        const float2* base = &sv[ty * LW + tx];
        float ta[K];
        #pragma unroll
        for (int mi = 0; mi < KS; ++mi)
            #pragma unroll
            for (int mj = 0; mj < KS; ++mj) {
                const float2 p = base[(mi * D) * LW + mj * D];
                ta[mi * KS + mj] = p.x;
                s  += p.x;
                s2  = fmaf(p.x, p.x, s2);
                sl += p.y;
            }
        const float mu = s * INVK;
        sad = 0.0f;
        #pragma unroll
        for (int i = 0; i < K; ++i) sad += fabsf(ta[i] - mu);
    } else {
        // Vertical stage: column sums over KS row taps, TH x LW plane (LDS).
        constexpr int NC = TH * LW;
        for (int e = tid; e < NC; e += 512) {
            const int r = e / LW;
            const int c = e - r * LW;
            const float2* cp = &sv[r * LW + c];
            float vs = 0.0f, vs2 = 0.0f, vsl = 0.0f;
            #pragma unroll
            for (int mi = 0; mi < KS; ++mi) {
                const float2 p = cp[(mi * D) * LW];
                vs  += p.x;
                vs2  = fmaf(p.x, p.x, vs2);
                vsl += p.y;
            }
            cs2[e] = make_float2(vs, vs2);
            cs1[e] = vsl;
        }
        __syncthreads();

        // Horizontal stage: KS taps over column sums (LDS).
        const float2* q2 = &cs2[ty * LW + tx];
        const float*  q1 = &cs1[ty * LW + tx];
        #pragma unroll
        for (int mj = 0; mj < KS; ++mj) {
            const float2 q = q2[mj * D];
            s  += q.x;
            s2 += q.y;
            sl += q1[mj * D];
        }
        const float mu = s * INVK;

        // ---- SAD from GLOBAL (different HW port than LDS). ----
        const int gh0 = h0 + ty - PAD;
        const int gw0 = w0 + tx - PAD;
        const bool interior = (h0 - PAD >= 0) && (h0 + TH - 1 + PAD < H) &&
                              (w0 - PAD >= 0) && (w0 + TW - 1 + PAD < W);
        sad = 0.0f;
        if (interior) {                   // block-uniform branch
            const float* tp = xp + (size_t)gh0 * W + gw0;
            #pragma unroll
            for (int mi = 0; mi < KS; ++mi) {
                const float* rp = tp + (size_t)(mi * D) * W;
                #pragma unroll
                for (int mj = 0; mj < KS; ++mj)
                    sad += fabsf(rp[mj * D] - mu);
            }
        } else {
            #pragma unroll
            for (int mi = 0; mi < KS; ++mi) {
                const int gh = gh0 + mi * D;
                const bool rok = (unsigned)gh < (unsigned)H;
                const float* rp = xp + (size_t)(rok ? gh : 0) * W;
                #pragma unroll
                for (int mj = 0; mj < KS; ++mj) {
                    const int gw = gw0 + mj * D;
                    const bool cok = (unsigned)gw < (unsigned)W;
                    float v = rp[cok ? gw : 0];
                    v = (rok && cok) ? v : 0.0f;
                    sad += fabsf(v - mu);
                }
            }
        }
    }

    const float mu       = s * INVK;
    const float energy   = s2 * INVK;
    const float var      = fmaxf(energy - mu * mu, 0.0f);
    const float sd       = sqrtf(var * UNB) + EPS;
    const float contrast = var / (sd * sd);
    const float entropy  = -sl * INVK;
    const float homog    = 1.0f / (1.0f + sad * INVK);

    const size_t fstride = (size_t)H * W;
    const size_t rowoff  = (size_t)(h0 + ty) * W;
    float* op = out + (size_t)bc * 4 * fstride + w0 + tx;
    __builtin_nontemporal_store((contrast + EPS) * INV_SQRT_E, &op[0 * fstride + rowoff]);
    __builtin_nontemporal_store((energy   + EPS) * INV_SQRT_E, &op[1 * fstride + rowoff]);
    __builtin_nontemporal_store((entropy  + EPS) * INV_SQRT_E, &op[2 * fstride + rowoff]);
    __builtin_nontemporal_store((homog    + EPS) * INV_SQRT_E, &op[3 * fstride + rowoff]);
}

__global__ __launch_bounds__(512, 8) void tex_fused(
    const float* __restrict__ x, float* __restrict__ out, int H, int W)
{
    extern __shared__ char smem[];
    const int dz = blockIdx.z & 3;       // dilation in fast bits: co-resident
    const int bc = blockIdx.z >> 2;      // blocks on a CU mix D1..D4
    const size_t per = (size_t)8 * 4 * H * W;
    switch (dz) {
        case 0: body<4>(x, out + 3 * per, smem, bc, H, W); break;
        case 1: body<3>(x, out + 2 * per, smem, bc, H, W); break;
        case 2: body<2>(x, out + 1 * per, smem, bc, H, W); break;
        default: body<1>(x, out + 0 * per, smem, bc, H, W); break;
    }
}

extern "C" void kernel_launch(void* const* d_in, const int* in_sizes, int n_in,
                              void* d_out, int out_size, void* d_ws, size_t ws_size,
                              hipStream_t stream) {
    const float* x = (const float*)d_in[0];
    float* out = (float*)d_out;

    const int H = 256, W = 256;
    // Per-D LDS (TH=8, PAD=D*D): sv LH*LW*8 + cs TH*LW*12
    //   D=4: LH=40, LW=96: 30720 + 9216 = 39936  (max) -> 4 blocks/CU
    //   D=3: LH=26, LW=82: 17056 + 7872 = 24928
    //   D=2: LH=16, LW=72:  9216 + 6912 = 16128
    //   D=1: LH=10, LW=66:  5280 (register path)
    const size_t smem_bytes = 39936;

    dim3 blk(64, 8, 1);
    dim3 grd(W / 64, H / 8, 8 * 4);      // 4 x-tiles, 32 y-tiles, (bc x dz)
    tex_fused<<<grd, blk, smem_bytes, stream>>>(x, out, H, W);
}

// Round 12
// 77.646 us; speedup vs baseline: 1.1361x; 1.1361x over previous
//
#include <hip/hip_runtime.h>
#include <cstddef>

#define EPS 1e-6f
constexpr float INV_SQRT_E = 0.6065306597126334f;  // exp(-0.5*THETA^2), THETA=1

// R9 config (TH=8, block (64,8), 39,936 B LDS -> 4 blocks/CU = 32 waves/CU)
// with three LDS-port optimizations:
//  1. SPLIT sx / slg planes (b32, stride-1, conflict-free) — R9's interleaved
//     float2 made SAD's .x-only reads stride-8B = 4-way bank conflict (1.58x).
//  2. SAD PAIR-WALK: rows (r, r+D) share KS-1 of KS tap rows; owner threads
//     (ty<4) walk KS+1 rows per column tap for 2 pixels (45 vs 81 reads/px
//     at D=4). mu/sad exchanged via planes aliased into dead cs space.
//  3. Vertical stage pair-walk (same sharing on column sums).
template <int D>
__device__ __forceinline__ void body(const float* __restrict__ x,
                                     float* __restrict__ out,
                                     char* smem, int bc, int H, int W)
{
    constexpr int PAD = D * D;          // halo per side
    constexpr int KS  = 2 * D + 1;      // taps per axis
    constexpr int K   = KS * KS;        // patch size
    constexpr int TW  = 64, TH = 8;
    constexpr int LW  = TW + 2 * PAD;
    constexpr int LH  = TH + 2 * PAD;
    constexpr int NE  = LH * LW;
    constexpr int NI  = (NE + 511) / 512;
    constexpr float INVK = 1.0f / (float)K;
    constexpr float UNB  = (float)K / (float)(K - 1);

    float*  sx  = (float*)smem;                 // [NE] v
    float*  slg = sx + NE;                      // [NE] v*log(v+eps)
    float2* cs2 = (float2*)(slg + NE);          // [TH*LW] {col_s, col_s2}
    float*  cs1 = (float*)(cs2 + TH * LW);      // [TH*LW] col_sl
    // Aliased exchange planes (cs2 region is dead after the horizontal stage;
    // needs 4096 B, cs2 has >= 4608 B for D>=2).
    float*  muP  = (float*)cs2;                 // [TH*64]
    float*  sadP = muP + TH * 64;               // [TH*64]

    const int w0 = blockIdx.x * TW;
    const int h0 = blockIdx.y * TH;
    const float* xp = x + (size_t)bc * H * W;
    const int tid = threadIdx.y * 64 + threadIdx.x;

    // ---- Staging: batched global loads, then split-plane LDS writes. ----
    float vb[NI];
    #pragma unroll
    for (int i = 0; i < NI; ++i) {
        const int idx = tid + i * 512;
        float v = 0.0f;
        if (idx < NE) {
            const int r  = idx / LW;
            const int cc = idx - r * LW;
            const int gh = h0 - PAD + r;
            const int gw = w0 - PAD + cc;
            if (gh >= 0 && gh < H && gw >= 0 && gw < W) v = xp[gh * W + gw];
        }
        vb[i] = v;
    }
    #pragma unroll
    for (int i = 0; i < NI; ++i) {
        const int idx = tid + i * 512;
        if (idx < NE) {
            sx[idx]  = vb[i];
            slg[idx] = vb[i] * __logf(vb[i] + EPS);   // v=0 -> exactly 0
        }
    }
    __syncthreads();

    const int tx = threadIdx.x;
    const int ty = threadIdx.y;

    if constexpr (K <= 9) {
        // ---- D=1: single pass, taps cached in registers. ----
        const float* bx = sx  + ty * LW + tx;
        const float* bl = slg + ty * LW + tx;
        float s = 0.f, s2 = 0.f, sl = 0.f, ta[K];
        #pragma unroll
        for (int mi = 0; mi < KS; ++mi)
            #pragma unroll
            for (int mj = 0; mj < KS; ++mj) {
                const float v = bx[mi * LW + mj];
                ta[mi * KS + mj] = v;
                s  += v;
                s2  = fmaf(v, v, s2);
                sl += bl[mi * LW + mj];
            }
        const float mu = s * INVK;
        float sad = 0.f;
        #pragma unroll
        for (int i = 0; i < K; ++i) sad += fabsf(ta[i] - mu);

        const float energy   = s2 * INVK;
        const float var      = fmaxf(energy - mu * mu, 0.f);
        const float sd       = sqrtf(var * UNB) + EPS;
        const float contrast = var / (sd * sd);
        const float entropy  = -sl * INVK;
        const float homog    = 1.f / (1.f + sad * INVK);
        const size_t fs = (size_t)H * W;
        const size_t ro = (size_t)(h0 + ty) * W;
        float* op = out + (size_t)bc * 4 * fs + w0 + tx;
        __builtin_nontemporal_store((contrast + EPS) * INV_SQRT_E, &op[0 * fs + ro]);
        __builtin_nontemporal_store((energy   + EPS) * INV_SQRT_E, &op[1 * fs + ro]);
        __builtin_nontemporal_store((entropy  + EPS) * INV_SQRT_E, &op[2 * fs + ro]);
        __builtin_nontemporal_store((homog    + EPS) * INV_SQRT_E, &op[3 * fs + ro]);
        return;
    } else {
        // ---- Vertical stage: PAIR-WALK column sums. Pairs over rows 0..7:
        //  D=2: (0,2)(1,3)(4,6)(5,7)  D=3: (0,3)(1,4)(2,5)+{6,7} indep
        //  D=4: (0,4)(1,5)(2,6)(3,7)
        for (int e = tid; e < 4 * LW; e += 512) {
            const int p = e / LW;
            const int c = e - p * LW;
            const int vA = (D == 2) ? ((p < 2) ? p : p + 2) : p;
            if (!(D == 3 && p == 3)) {
                const int vB = vA + D;
                const float* cx = sx  + vA * LW + c;
                const float* cl = slg + vA * LW + c;
                float sA = 0, qA = 0, lA = 0, sB = 0, qB = 0, lB = 0;
                #pragma unroll
                for (int t = 0; t <= KS; ++t) {
                    const float v = cx[t * D * LW];
                    const float g = cl[t * D * LW];
                    if (t < KS)  { sA += v; qA = fmaf(v, v, qA); lA += g; }
                    if (t >= 1)  { sB += v; qB = fmaf(v, v, qB); lB += g; }
                }
                cs2[vA * LW + c] = make_float2(sA, qA); cs1[vA * LW + c] = lA;
                cs2[vB * LW + c] = make_float2(sB, qB); cs1[vB * LW + c] = lB;
            } else {            // D=3 leftover rows 6,7: independent walks
                #pragma unroll
                for (int rr = 6; rr <= 7; ++rr) {
                    const float* cx = sx  + rr * LW + c;
                    const float* cl = slg + rr * LW + c;
                    float s = 0, q = 0, l = 0;
                    #pragma unroll
                    for (int mi = 0; mi < KS; ++mi) {
                        const float v = cx[mi * D * LW];
                        s += v; q = fmaf(v, v, q); l += cl[mi * D * LW];
                    }
                    cs2[rr * LW + c] = make_float2(s, q); cs1[rr * LW + c] = l;
                }
            }
        }
        __syncthreads();

        // ---- Horizontal stage: KS taps over column sums. ----
        float s = 0.f, s2 = 0.f, sl = 0.f;
        const float2* q2 = cs2 + ty * LW + tx;
        const float*  q1 = cs1 + ty * LW + tx;
        #pragma unroll
        for (int mj = 0; mj < KS; ++mj) {
            const float2 q = q2[mj * D];
            s += q.x; s2 += q.y; sl += q1[mj * D];
        }
        const float mu = s * INVK;
        __syncthreads();                 // cs reads done; muP may alias cs2

        muP[ty * 64 + tx] = mu;
        __syncthreads();

        // ---- SAD: pair-walk by owner threads (waves 0..3). ----
        if (ty < 4) {
            const int o = ty;
            if (!(D == 3 && o == 3)) {
                const int rA = (D == 2) ? ((o < 2) ? o : o + 2) : o;
                const int rB = rA + D;
                const float muA = muP[rA * 64 + tx];
                const float muB = muP[rB * 64 + tx];
                float sadA = 0.f, sadB = 0.f;
                const float* bp = sx + rA * LW + tx;
                #pragma unroll
                for (int mj = 0; mj < KS; ++mj) {
                    const float* cp = bp + mj * D;
                    #pragma unroll
                    for (int t = 0; t <= KS; ++t) {
                        const float v = cp[t * D * LW];
                        if (t < KS) sadA += fabsf(v - muA);
                        if (t >= 1) sadB += fabsf(v - muB);
                    }
                }
                sadP[rA * 64 + tx] = sadA;
                sadP[rB * 64 + tx] = sadB;
            } else {             // D=3 leftover rows 6,7: full K walks
                #pragma unroll
                for (int rr = 6; rr <= 7; ++rr) {
                    const float mur = muP[rr * 64 + tx];
                    const float* bp = sx + rr * LW + tx;
                    float sd = 0.f;
                    #pragma unroll
                    for (int mi = 0; mi < KS; ++mi)
                        #pragma unroll
                        for (int mj = 0; mj < KS; ++mj)
                            sd += fabsf(bp[mi * D * LW + mj * D] - mur);
                    sadP[rr * 64 + tx] = sd;
                }
            }
        }
        __syncthreads();
        const float sad = sadP[ty * 64 + tx];

        // ---- Epilogue. ----
        const float energy   = s2 * INVK;
        const float var      = fmaxf(energy - mu * mu, 0.f);
        const float sd       = sqrtf(var * UNB) + EPS;
        const float contrast = var / (sd * sd);
        const float entropy  = -sl * INVK;
        const float homog    = 1.f / (1.f + sad * INVK);
        const size_t fs = (size_t)H * W;
        const size_t ro = (size_t)(h0 + ty) * W;
        float* op = out + (size_t)bc * 4 * fs + w0 + tx;
        __builtin_nontemporal_store((contrast + EPS) * INV_SQRT_E, &op[0 * fs + ro]);
        __builtin_nontemporal_store((energy   + EPS) * INV_SQRT_E, &op[1 * fs + ro]);
        __builtin_nontemporal_store((entropy  + EPS) * INV_SQRT_E, &op[2 * fs + ro]);
        __builtin_nontemporal_store((homog    + EPS) * INV_SQRT_E, &op[3 * fs + ro]);
    }
}

__global__ __launch_bounds__(512, 8) void tex_fused(
    const float* __restrict__ x, float* __restrict__ out, int H, int W)
{
    extern __shared__ __align__(16) char smem[];
    const int dz = blockIdx.z & 3;       // dilation in fast bits: co-resident
    const int bc = blockIdx.z >> 2;      // blocks on a CU mix D1..D4
    const size_t per = (size_t)8 * 4 * H * W;
    switch (dz) {
        case 0: body<4>(x, out + 3 * per, smem, bc, H, W); break;
        case 1: body<3>(x, out + 2 * per, smem, bc, H, W); break;
        case 2: body<2>(x, out + 1 * per, smem, bc, H, W); break;
        default: body<1>(x, out + 0 * per, smem, bc, H, W); break;
    }
}

extern "C" void kernel_launch(void* const* d_in, const int* in_sizes, int n_in,
                              void* d_out, int out_size, void* d_ws, size_t ws_size,
                              hipStream_t stream) {
    const float* x = (const float*)d_in[0];
    float* out = (float*)d_out;

    const int H = 256, W = 256;
    // Per-D LDS (TH=8, PAD=D*D): 2 b32 planes LH*LW*8 + cs2 TH*LW*8 + cs1 TH*LW*4
    //   D=4: LH=40, LW=96: 30720 + 6144 + 3072 = 39936  (max) -> 4 blocks/CU
    //   D=3: LH=26, LW=82: 17056 + 5248 + 2624 = 24928
    //   D=2: LH=16, LW=72:  9216 + 4608 + 2304 = 16128
    //   D=1: LH=10, LW=66:  5280 (register path; cs unused)
    const size_t smem_bytes = 39936;

    dim3 blk(64, 8, 1);
    dim3 grd(W / 64, H / 8, 8 * 4);      // 4 x-tiles, 32 y-tiles, (bc x dz)
    tex_fused<<<grd, blk, smem_bytes, stream>>>(x, out, H, W);
}